// Round 1
// baseline (846.061 us; speedup 1.0000x reference)
//
#include <hip/hip_runtime.h>
#include <math.h>

#define Bb 8
#define Tt 512
#define Ff 256
#define Cc 16          // gate output channels
#define TF (Tt*Ff)

__device__ __forceinline__ float fast_sigmoid(float x) { return 1.0f / (1.0f + __expf(-x)); }
__device__ __forceinline__ float fast_tanh(float x)    { return 1.0f - 2.0f / (__expf(2.0f * x) + 1.0f); }

// One block per (t, b). 256 threads = 8 channel-groups (cg) x 32 f-groups.
// Each thread: 4 conv-out channels {2cg, 2cg+1, 2cg+16, 2cg+17} x 8 consecutive f.
// Register sliding window over f (compile-time indices via DIL template).
template<int DIL, int CIN>
__global__ __launch_bounds__(256)
void gate_kernel(const float* __restrict__ x, const float* __restrict__ w,
                 const float* __restrict__ bias, const float* __restrict__ gamma,
                 const float* __restrict__ beta, const float* __restrict__ mean,
                 const float* __restrict__ var, float* __restrict__ out)
{
    constexpr int OFF = (DIL == 8) ? 8 : 4;
    constexpr int WB  = (DIL == 8) ? 24 : 16;   // register window width
    __shared__ float wlds[CIN * 32 * 9];

    const int t   = blockIdx.x;
    const int b   = blockIdx.y;
    const int tid = threadIdx.x;
    const int cg  = tid >> 5;
    const int f0  = (tid & 31) * 8;

    // cooperative weight load into LDS, layout: [ci][cg][j][k]  (j: 4 chans, k: 9 taps)
    for (int idx = tid; idx < CIN * 32 * 9; idx += 256) {
        int ci  = idx / 288;
        int r   = idx - ci * 288;
        int cgi = r / 36;
        int r2  = r - cgi * 36;
        int j   = r2 / 9;
        int k   = r2 - j * 9;
        int co  = 2 * cgi + (j & 1) + (j >> 1) * 16;
        wlds[idx] = w[(co * CIN + ci) * 9 + k];
    }
    __syncthreads();

    // fold BN into scale/shift; conv bias as accumulator init
    float bns[4], bno[4], acc[4][8];
    #pragma unroll
    for (int j = 0; j < 4; j++) {
        int c = 2 * cg + (j & 1) + (j >> 1) * 16;
        float s = gamma[c] * rsqrtf(var[c] + 1e-5f);
        bns[j] = s;
        bno[j] = beta[c] - mean[c] * s;
        float bi = bias[c];
        #pragma unroll
        for (int q = 0; q < 8; q++) acc[j][q] = bi;
    }

    for (int ci = 0; ci < CIN; ci++) {
        float wr[36];
        const float4* wv = (const float4*)(wlds + ci * 288 + cg * 36);
        #pragma unroll
        for (int v = 0; v < 9; v++) ((float4*)wr)[v] = wv[v];

        #pragma unroll
        for (int dt = 0; dt < 3; dt++) {
            int t_in = t + (dt - 1) * DIL;
            bool trow = (t_in >= 0) && (t_in < Tt);
            const float* rowp = x + ((size_t)(b * CIN + ci) * Tt + (trow ? t_in : 0)) * Ff;
            float buf[WB];
            #pragma unroll
            for (int v = 0; v < WB / 4; v++) {
                int fb = f0 - OFF + v * 4;
                float4 val = make_float4(0.f, 0.f, 0.f, 0.f);
                if (trow && fb >= 0 && fb <= Ff - 4)
                    val = *(const float4*)(rowp + fb);
                buf[v * 4 + 0] = val.x; buf[v * 4 + 1] = val.y;
                buf[v * 4 + 2] = val.z; buf[v * 4 + 3] = val.w;
            }
            #pragma unroll
            for (int kf = 0; kf < 3; kf++) {
                #pragma unroll
                for (int j = 0; j < 4; j++) {
                    float wj = wr[j * 9 + dt * 3 + kf];
                    #pragma unroll
                    for (int q = 0; q < 8; q++)
                        acc[j][q] = fmaf(buf[OFF + q + (kf - 1) * DIL], wj, acc[j][q]);
                }
            }
        }
    }

    // BN + GLU epilogue: out channel 2cg+jj = tanh(a)*sigmoid(g)
    #pragma unroll
    for (int jj = 0; jj < 2; jj++) {
        float res[8];
        #pragma unroll
        for (int q = 0; q < 8; q++) {
            float a = acc[jj][q]     * bns[jj]     + bno[jj];
            float g = acc[jj + 2][q] * bns[jj + 2] + bno[jj + 2];
            res[q] = fast_tanh(a) * fast_sigmoid(g);
        }
        float* op = out + ((size_t)(b * Cc + 2 * cg + jj) * Tt + t) * Ff + f0;
        *(float4*)(op)     = make_float4(res[0], res[1], res[2], res[3]);
        *(float4*)(op + 4) = make_float4(res[4], res[5], res[6], res[7]);
    }
}

// One thread per (b, g, f) sequence. PyTorch gate order r,z,n. H=2, I=2.
// Emits partial out-conv dot: h0*out_w[2g] + h1*out_w[2g+1] into part[b][g][t][f].
__global__ __launch_bounds__(64)
void gru_kernel(const float* __restrict__ xin,   // (B,16,T,F) gate4 output
                const float* __restrict__ wih,   // (8,6,2)
                const float* __restrict__ whh,   // (8,6,2)
                const float* __restrict__ bih,   // (8,6)
                const float* __restrict__ bhh,   // (8,6)
                const float* __restrict__ out_w, // (16)
                float* __restrict__ part)        // (B,8,T,F)
{
    const int f = (blockIdx.x & 3) * 64 + threadIdx.x;
    const int g = (blockIdx.x >> 2) & 7;
    const int b = blockIdx.x >> 5;

    float Wih[6][2], Whh[6][2], Bih[6], Bhh[6];
    #pragma unroll
    for (int k = 0; k < 6; k++) {
        Wih[k][0] = wih[g * 12 + k * 2 + 0];
        Wih[k][1] = wih[g * 12 + k * 2 + 1];
        Whh[k][0] = whh[g * 12 + k * 2 + 0];
        Whh[k][1] = whh[g * 12 + k * 2 + 1];
        Bih[k] = bih[g * 6 + k];
        Bhh[k] = bhh[g * 6 + k];
    }
    const float ow0 = out_w[2 * g], ow1 = out_w[2 * g + 1];

    const float* p0 = xin + (size_t)(b * Cc + 2 * g) * TF + f;
    const float* p1 = p0 + TF;
    float* po = part + (size_t)(b * 8 + g) * TF + f;

    float h0 = 0.f, h1 = 0.f;
    float x0 = p0[0], x1 = p1[0];
    for (int t = 0; t < Tt; t++) {
        float nx0 = 0.f, nx1 = 0.f;
        if (t + 1 < Tt) { nx0 = p0[(t + 1) * Ff]; nx1 = p1[(t + 1) * Ff]; }
        float gi[6], gh[6];
        #pragma unroll
        for (int k = 0; k < 6; k++) {
            gi[k] = fmaf(Wih[k][0], x0, fmaf(Wih[k][1], x1, Bih[k]));
            gh[k] = fmaf(Whh[k][0], h0, fmaf(Whh[k][1], h1, Bhh[k]));
        }
        float r0 = fast_sigmoid(gi[0] + gh[0]);
        float r1 = fast_sigmoid(gi[1] + gh[1]);
        float z0 = fast_sigmoid(gi[2] + gh[2]);
        float z1 = fast_sigmoid(gi[3] + gh[3]);
        float n0 = fast_tanh(gi[4] + r0 * gh[4]);
        float n1 = fast_tanh(gi[5] + r1 * gh[5]);
        h0 = (1.0f - z0) * n0 + z0 * h0;
        h1 = (1.0f - z1) * n1 + z1 * h1;
        po[t * Ff] = fmaf(h0, ow0, h1 * ow1);
        x0 = nx0; x1 = nx1;
    }
}

// Sum the 8 group partials + out_b -> final (B,1,T,F)
__global__ __launch_bounds__(256)
void out_kernel(const float* __restrict__ part, const float* __restrict__ out_b,
                float* __restrict__ out)
{
    int idx = (blockIdx.x * 256 + threadIdx.x) * 4;
    int b = idx / TF;
    int r = idx - b * TF;
    const float4* p = (const float4*)(part + (size_t)b * 8 * TF + r);
    float ob = out_b[0];
    float4 s = make_float4(ob, ob, ob, ob);
    #pragma unroll
    for (int g = 0; g < 8; g++) {
        float4 v = p[(size_t)g * (TF / 4)];
        s.x += v.x; s.y += v.y; s.z += v.z; s.w += v.w;
    }
    *(float4*)(out + idx) = s;
}

extern "C" void kernel_launch(void* const* d_in, const int* in_sizes, int n_in,
                              void* d_out, int out_size, void* d_ws, size_t ws_size,
                              hipStream_t stream) {
    const float* x = (const float*)d_in[0];
    float* buf0 = (float*)d_ws;                       // 16,777,216 floats (67.1 MB)
    float* buf1 = buf0 + (size_t)Bb * Cc * TF;        // second 67.1 MB

    dim3 grid(Tt, Bb), blk(256);
    gate_kernel<1, 2><<<grid, blk, 0, stream>>>(
        x, (const float*)d_in[1], (const float*)d_in[2], (const float*)d_in[3],
        (const float*)d_in[4], (const float*)d_in[5], (const float*)d_in[6], buf0);
    gate_kernel<2, 16><<<grid, blk, 0, stream>>>(
        buf0, (const float*)d_in[7], (const float*)d_in[8], (const float*)d_in[9],
        (const float*)d_in[10], (const float*)d_in[11], (const float*)d_in[12], buf1);
    gate_kernel<4, 16><<<grid, blk, 0, stream>>>(
        buf1, (const float*)d_in[13], (const float*)d_in[14], (const float*)d_in[15],
        (const float*)d_in[16], (const float*)d_in[17], (const float*)d_in[18], buf0);
    gate_kernel<8, 16><<<grid, blk, 0, stream>>>(
        buf0, (const float*)d_in[19], (const float*)d_in[20], (const float*)d_in[21],
        (const float*)d_in[22], (const float*)d_in[23], (const float*)d_in[24], buf1);

    // GRU reads buf1 (gate4 out), writes partials into buf0 (first 33.5 MB)
    gru_kernel<<<Bb * 8 * 4, 64, 0, stream>>>(
        buf1, (const float*)d_in[25], (const float*)d_in[26], (const float*)d_in[27],
        (const float*)d_in[28], (const float*)d_in[29], buf0);

    out_kernel<<<(Bb * TF / 4) / 256, 256, 0, stream>>>(
        buf0, (const float*)d_in[30], (float*)d_out);
}

// Round 2
// 657.306 us; speedup vs baseline: 1.2872x; 1.2872x over previous
//
#include <hip/hip_runtime.h>
#include <math.h>

#define Bb 8
#define Tt 512
#define Ff 256
#define Cc 16
#define TF (Tt*Ff)
#define TROW 528
#define FROW 272
#define CELL 64
#define ROWBYTES (FROW*CELL)                       // 17408
#define BUFBYTES ((size_t)Bb*TROW*FROW*CELL)       // 73,531,392

typedef __attribute__((ext_vector_type(8))) short short8;
typedef __attribute__((ext_vector_type(4))) float f32x4;

typedef const __attribute__((address_space(1))) void* gas1_t;
typedef __attribute__((address_space(3))) void* las3_t;
#define GLOAD_LDS(g, l) __builtin_amdgcn_global_load_lds((gas1_t)(const void*)(g), (las3_t)(void*)(l), 16, 0, 0)

__device__ __forceinline__ float fast_sigmoid(float x) { return 1.0f / (1.0f + __expf(-x)); }
__device__ __forceinline__ float fast_tanh(float x)    { return 1.0f - 2.0f / (__expf(2.0f * x) + 1.0f); }

__device__ __forceinline__ unsigned short bf16_rne(float x) {
    unsigned u = __float_as_uint(x);
    u += 0x7fffu + ((u >> 16) & 1u);
    return (unsigned short)(u >> 16);
}
__device__ __forceinline__ float bf16_to_f(unsigned short h) {
    return __uint_as_float(((unsigned)h) << 16);
}
__device__ __forceinline__ f32x4 mfma_bf16(short8 a, short8 b, f32x4 c) {
    return __builtin_amdgcn_mfma_f32_16x16x32_bf16(a, b, c, 0, 0, 0);
}

// ---------- zero the halo pads of bufA and bufB (re-poisoned every launch) ----------
__global__ __launch_bounds__(256) void padzero(char* __restrict__ bufA, char* __restrict__ bufB)
{
    int idx = blockIdx.x * 256 + threadIdx.x;      // 200704 cells total
    int which = idx >= 100352;
    int r0 = which ? idx - 100352 : idx;
    int b = r0 / 12544, c = r0 - b * 12544;
    int tp, fp;
    if (c < 4352) { int row = c / 272; fp = c - row * 272; tp = row < 8 ? row : 512 + row; }
    else { int c2 = c - 4352; tp = 8 + (c2 >> 4); int fi = c2 & 15; fp = fi < 8 ? fi : 256 + fi; }
    char* base = (which ? bufB : bufA) + ((size_t)(b * TROW + tp) * FROW + fp) * CELL;
    float4 z = make_float4(0.f, 0.f, 0.f, 0.f);
    float4* p = (float4*)base;
    p[0] = z; p[1] = z; p[2] = z; p[3] = z;
}

// ---------- fold BN into weights, split bf16 hi/lo, write swizzled A-fragment layout ----------
__global__ __launch_bounds__(256) void wsetup(const float* __restrict__ w, const float* __restrict__ bias,
                       const float* __restrict__ gamma, const float* __restrict__ beta,
                       const float* __restrict__ mean, const float* __restrict__ var,
                       char* __restrict__ wpre, float* __restrict__ bpre)
{
    int tid = threadIdx.x;
    if (tid < 32) {
        float s = gamma[tid] * rsqrtf(var[tid] + 1e-5f);
        bpre[tid] = (bias[tid] - mean[tid]) * s + beta[tid];
    }
    for (int i = tid; i < 4608; i += 256) {
        int co = i / 144, r = i - co * 144;
        int ci = r / 9, tap = r - ci * 9;
        float s = gamma[co] * rsqrtf(var[co] + 1e-5f);
        float wv = w[(co * 16 + ci) * 9 + tap] * s;
        unsigned short hi = bf16_rne(wv);
        unsigned short lo = bf16_rne(wv - bf16_to_f(hi));
        int ks = tap >> 1, tp = tap & 1;
        int kl = tp * 16 + ci;
        int qq = kl >> 3, jj = kl & 7;
        int sub = qq ^ (co & 3);
        *(unsigned short*)(wpre + ((0 * 5 + ks) * 32 + co) * 64 + sub * 16 + jj * 2) = hi;
        *(unsigned short*)(wpre + ((1 * 5 + ks) * 32 + co) * 64 + sub * 16 + jj * 2) = lo;
    }
    // zero the pad half of k-step 4 (k_local 16..31), both planes
    for (int i = tid; i < 1024; i += 256) {
        int p = i >> 9, rem = i & 511;
        int co = rem >> 4, kl = 16 + (rem & 15);
        int qq = kl >> 3, jj = kl & 7;
        int sub = qq ^ (co & 3);
        *(unsigned short*)(wpre + ((p * 5 + 4) * 32 + co) * 64 + sub * 16 + jj * 2) = 0;
    }
}

// ---------- conv1 (CIN=2, dil=1): vector kernel, writes padded swizzled bf16 hi/lo layout ----------
__global__ __launch_bounds__(256)
void gate1_kernel(const float* __restrict__ x, const float* __restrict__ w,
                  const float* __restrict__ bias, const float* __restrict__ gamma,
                  const float* __restrict__ beta, const float* __restrict__ mean,
                  const float* __restrict__ var, char* __restrict__ outBuf)
{
    constexpr int CIN = 2;
    __shared__ float wlds[CIN * 32 * 9];
    const int t = blockIdx.x, b = blockIdx.y;
    const int tid = threadIdx.x;
    const int cg = tid >> 5;
    const int f0 = (tid & 31) * 8;

    for (int idx = tid; idx < CIN * 32 * 9; idx += 256) {
        int ci = idx / 288, r = idx - ci * 288;
        int cgi = r / 36, r2 = r - cgi * 36;
        int j = r2 / 9, k = r2 - j * 9;
        int co = 2 * cgi + (j & 1) + (j >> 1) * 16;
        wlds[idx] = w[(co * CIN + ci) * 9 + k];
    }
    __syncthreads();

    float bns[4], bno[4], acc[4][8];
    #pragma unroll
    for (int j = 0; j < 4; j++) {
        int c = 2 * cg + (j & 1) + (j >> 1) * 16;
        float s = gamma[c] * rsqrtf(var[c] + 1e-5f);
        bns[j] = s; bno[j] = beta[c] - mean[c] * s;
        float bi = bias[c];
        #pragma unroll
        for (int q = 0; q < 8; q++) acc[j][q] = bi;
    }

    for (int ci = 0; ci < CIN; ci++) {
        float wr[36];
        const float4* wv4 = (const float4*)(wlds + ci * 288 + cg * 36);
        #pragma unroll
        for (int v = 0; v < 9; v++) ((float4*)wr)[v] = wv4[v];
        #pragma unroll
        for (int dt = 0; dt < 3; dt++) {
            int t_in = t + dt - 1;
            bool trow = (t_in >= 0) && (t_in < Tt);
            const float* rowp = x + ((size_t)(b * CIN + ci) * Tt + (trow ? t_in : 0)) * Ff;
            float buf[16];
            #pragma unroll
            for (int v = 0; v < 4; v++) {
                int fb = f0 - 4 + v * 4;
                float4 val = make_float4(0.f, 0.f, 0.f, 0.f);
                if (trow && fb >= 0 && fb <= Ff - 4) val = *(const float4*)(rowp + fb);
                buf[v*4+0] = val.x; buf[v*4+1] = val.y; buf[v*4+2] = val.z; buf[v*4+3] = val.w;
            }
            #pragma unroll
            for (int kf = 0; kf < 3; kf++)
                #pragma unroll
                for (int j = 0; j < 4; j++) {
                    float wj = wr[j * 9 + dt * 3 + kf];
                    #pragma unroll
                    for (int q = 0; q < 8; q++)
                        acc[j][q] = fmaf(buf[4 + q + kf - 1], wj, acc[j][q]);
                }
        }
    }

    float res[2][8];
    #pragma unroll
    for (int jj = 0; jj < 2; jj++)
        #pragma unroll
        for (int q = 0; q < 8; q++) {
            float a = acc[jj][q] * bns[jj] + bno[jj];
            float g = acc[jj + 2][q] * bns[jj + 2] + bno[jj + 2];
            res[jj][q] = fast_tanh(a) * fast_sigmoid(g);
        }
    // write 2 channels (2cg, 2cg+1) hi+lo into swizzled cells
    #pragma unroll
    for (int q = 0; q < 8; q++) {
        int fp = f0 + q + 8;
        char* cell = outBuf + ((size_t)(b * TROW + t + 8) * FROW + fp) * CELL;
        unsigned short h0 = bf16_rne(res[0][q]), h1 = bf16_rne(res[1][q]);
        unsigned short l0 = bf16_rne(res[0][q] - bf16_to_f(h0));
        unsigned short l1 = bf16_rne(res[1][q] - bf16_to_f(h1));
        unsigned hw = (unsigned)h0 | ((unsigned)h1 << 16);
        unsigned lw = (unsigned)l0 | ((unsigned)l1 << 16);
        int inner = (4 * cg) & 15;
        int sub_hi = (cg >> 2) ^ (fp & 3);
        int sub_lo = (2 + (cg >> 2)) ^ (fp & 3);
        *(unsigned*)(cell + sub_hi * 16 + inner) = hw;
        *(unsigned*)(cell + sub_lo * 16 + inner) = lw;
    }
}

// ---------- convs 2-4: MFMA implicit GEMM, bf16 hi/lo 3-pass ----------
template<int DIL, int WRITE_F32>
__global__ __launch_bounds__(256, 2)
void gate_mfma(const char* __restrict__ actIn, const char* __restrict__ wpre,
               const float* __restrict__ bpre, char* __restrict__ outBuf)
{
    __shared__ char actL[3 * ROWBYTES];    // 52224 B
    const int t = blockIdx.x, b = blockIdx.y;
    const int tid = threadIdx.x;
    const int wv = tid >> 6, lane = tid & 63;
    const int n = lane & 15, q = lane >> 4;

    // A-fragments (weights) from global (L2-hot), registers
    short8 aH[5][2], aL[5][2];
    #pragma unroll
    for (int ks = 0; ks < 5; ks++)
        #pragma unroll
        for (int ct = 0; ct < 2; ct++) {
            int co = ct * 16 + n;
            int sub = q ^ (co & 3);
            aH[ks][ct] = *(const short8*)(wpre + (size_t)((0 * 5 + ks) * 32 + co) * 64 + sub * 16);
            aL[ks][ct] = *(const short8*)(wpre + (size_t)((5 + ks) * 32 + co) * 64 + sub * 16);
        }

    // stage 3 act rows (t-d, t, t+d), contiguous 1088 chunks each
    #pragma unroll
    for (int r = 0; r < 3; r++) {
        int tp = t + 8 + (r - 1) * DIL;
        const char* src = actIn + ((size_t)(b * TROW + tp) * FROW) * CELL;
        char* dst = actL + r * ROWBYTES;
        #pragma unroll
        for (int i = 0; i < 4; i++)
            GLOAD_LDS(src + (i * 256 + tid) * 16, dst + (i * 256 + wv * 64) * 16);
        if (tid < 64)
            GLOAD_LDS(src + (1024 + lane) * 16, dst + 1024 * 16);
    }
    __syncthreads();

    const int fb = wv * 64;
    f32x4 acc[4][2] = {};

    #pragma unroll
    for (int ks = 0; ks < 5; ks++) {
        const int tapA = 2 * ks;
        const int tapB = (2 * ks + 1 > 8) ? 8 : 2 * ks + 1;
        const int rowA = tapA / 3, dfA = (tapA % 3 - 1) * DIL;
        const int rowB = tapB / 3, dfB = (tapB % 3 - 1) * DIL;
        int tapSel = q >> 1;
        int row = tapSel ? rowB : rowA;
        int df  = tapSel ? dfB : dfA;
        int cih = q & 1;
        const char* rbase = actL + row * ROWBYTES;
        #pragma unroll
        for (int nt = 0; nt < 4; nt++) {
            int fp = fb + nt * 16 + n + 8 + df;
            const char* cell = rbase + fp * CELL;
            short8 bH = *(const short8*)(cell + ((cih) ^ (fp & 3)) * 16);
            short8 bL = *(const short8*)(cell + ((2 + cih) ^ (fp & 3)) * 16);
            #pragma unroll
            for (int ct = 0; ct < 2; ct++) {
                acc[nt][ct] = mfma_bf16(aH[ks][ct], bH, acc[nt][ct]);
                acc[nt][ct] = mfma_bf16(aL[ks][ct], bH, acc[nt][ct]);
                acc[nt][ct] = mfma_bf16(aH[ks][ct], bL, acc[nt][ct]);
            }
        }
    }

    // epilogue: GLU, then store
    float4 bA = *(const float4*)(bpre + q * 4);
    float4 bG = *(const float4*)(bpre + 16 + q * 4);
    #pragma unroll
    for (int nt = 0; nt < 4; nt++) {
        float r[4];
        r[0] = fast_tanh(acc[nt][0].x + bA.x) * fast_sigmoid(acc[nt][1].x + bG.x);
        r[1] = fast_tanh(acc[nt][0].y + bA.y) * fast_sigmoid(acc[nt][1].y + bG.y);
        r[2] = fast_tanh(acc[nt][0].z + bA.z) * fast_sigmoid(acc[nt][1].z + bG.z);
        r[3] = fast_tanh(acc[nt][0].w + bA.w) * fast_sigmoid(acc[nt][1].w + bG.w);
        int f = fb + nt * 16 + n;
        if (WRITE_F32) {
            float* gp = (float*)outBuf;
            #pragma unroll
            for (int j = 0; j < 4; j++)
                gp[((size_t)(b * 16 + q * 4 + j) * Tt + t) * Ff + f] = r[j];
        } else {
            int fp = f + 8;
            char* cell = outBuf + ((size_t)(b * TROW + t + 8) * FROW + fp) * CELL;
            unsigned short h[4], l[4];
            #pragma unroll
            for (int j = 0; j < 4; j++) {
                h[j] = bf16_rne(r[j]);
                l[j] = bf16_rne(r[j] - bf16_to_f(h[j]));
            }
            uint2 hw, lw;
            hw.x = (unsigned)h[0] | ((unsigned)h[1] << 16);
            hw.y = (unsigned)h[2] | ((unsigned)h[3] << 16);
            lw.x = (unsigned)l[0] | ((unsigned)l[1] << 16);
            lw.y = (unsigned)l[2] | ((unsigned)l[3] << 16);
            int inner = (q & 1) * 8;
            *(uint2*)(cell + (((q >> 1) ^ (fp & 3)) * 16) + inner) = hw;
            *(uint2*)(cell + (((2 + (q >> 1)) ^ (fp & 3)) * 16) + inner) = lw;
        }
    }
}

// ---------- grouped GRU (H=2) + fused out_w partial dot, 4-deep prefetch ----------
__global__ __launch_bounds__(64)
void gru_kernel(const float* __restrict__ xin, const float* __restrict__ wih,
                const float* __restrict__ whh, const float* __restrict__ bih,
                const float* __restrict__ bhh, const float* __restrict__ out_w,
                float* __restrict__ part)
{
    const int f = (blockIdx.x & 3) * 64 + threadIdx.x;
    const int g = (blockIdx.x >> 2) & 7;
    const int b = blockIdx.x >> 5;

    float Wih[6][2], Whh[6][2], Bih[6], Bhh[6];
    #pragma unroll
    for (int k = 0; k < 6; k++) {
        Wih[k][0] = wih[g * 12 + k * 2 + 0];
        Wih[k][1] = wih[g * 12 + k * 2 + 1];
        Whh[k][0] = whh[g * 12 + k * 2 + 0];
        Whh[k][1] = whh[g * 12 + k * 2 + 1];
        Bih[k] = bih[g * 6 + k];
        Bhh[k] = bhh[g * 6 + k];
    }
    const float ow0 = out_w[2 * g], ow1 = out_w[2 * g + 1];
    const float* p0 = xin + (size_t)(b * Cc + 2 * g) * TF + f;
    const float* p1 = p0 + TF;
    float* po = part + (size_t)(b * 8 + g) * TF + f;

    float h0 = 0.f, h1 = 0.f;
    float xa[4], xb[4];
    #pragma unroll
    for (int j = 0; j < 4; j++) { xa[j] = p0[j * Ff]; xb[j] = p1[j * Ff]; }

    for (int t0 = 0; t0 < Tt; t0 += 4) {
        bool pf = (t0 < Tt - 4);
        #pragma unroll
        for (int j = 0; j < 4; j++) {
            int t = t0 + j;
            float x0 = xa[j], x1 = xb[j];
            if (pf) { xa[j] = p0[(t + 4) * Ff]; xb[j] = p1[(t + 4) * Ff]; }
            float gi[6], gh[6];
            #pragma unroll
            for (int k = 0; k < 6; k++) {
                gi[k] = fmaf(Wih[k][0], x0, fmaf(Wih[k][1], x1, Bih[k]));
                gh[k] = fmaf(Whh[k][0], h0, fmaf(Whh[k][1], h1, Bhh[k]));
            }
            float r0 = fast_sigmoid(gi[0] + gh[0]);
            float r1 = fast_sigmoid(gi[1] + gh[1]);
            float z0 = fast_sigmoid(gi[2] + gh[2]);
            float z1 = fast_sigmoid(gi[3] + gh[3]);
            float n0 = fast_tanh(gi[4] + r0 * gh[4]);
            float n1 = fast_tanh(gi[5] + r1 * gh[5]);
            h0 = (1.0f - z0) * n0 + z0 * h0;
            h1 = (1.0f - z1) * n1 + z1 * h1;
            po[t * Ff] = fmaf(h0, ow0, h1 * ow1);
        }
    }
}

__global__ __launch_bounds__(256)
void out_kernel(const float* __restrict__ part, const float* __restrict__ out_b,
                float* __restrict__ out)
{
    int idx = (blockIdx.x * 256 + threadIdx.x) * 4;
    int b = idx / TF;
    int r = idx - b * TF;
    const float4* p = (const float4*)(part + (size_t)b * 8 * TF + r);
    float ob = out_b[0];
    float4 s = make_float4(ob, ob, ob, ob);
    #pragma unroll
    for (int g = 0; g < 8; g++) {
        float4 v = p[(size_t)g * (TF / 4)];
        s.x += v.x; s.y += v.y; s.z += v.z; s.w += v.w;
    }
    *(float4*)(out + idx) = s;
}

extern "C" void kernel_launch(void* const* d_in, const int* in_sizes, int n_in,
                              void* d_out, int out_size, void* d_ws, size_t ws_size,
                              hipStream_t stream) {
    char* bufA = (char*)d_ws;
    char* bufB = bufA + BUFBYTES;
    char* wpre = bufB + BUFBYTES;
    float* bpre = (float*)(wpre + 3 * 20480);

    padzero<<<784, 256, 0, stream>>>(bufA, bufB);
    wsetup<<<1, 256, 0, stream>>>((const float*)d_in[7],  (const float*)d_in[8],  (const float*)d_in[9],
                                  (const float*)d_in[10], (const float*)d_in[11], (const float*)d_in[12],
                                  wpre, bpre);
    wsetup<<<1, 256, 0, stream>>>((const float*)d_in[13], (const float*)d_in[14], (const float*)d_in[15],
                                  (const float*)d_in[16], (const float*)d_in[17], (const float*)d_in[18],
                                  wpre + 20480, bpre + 32);
    wsetup<<<1, 256, 0, stream>>>((const float*)d_in[19], (const float*)d_in[20], (const float*)d_in[21],
                                  (const float*)d_in[22], (const float*)d_in[23], (const float*)d_in[24],
                                  wpre + 40960, bpre + 64);

    dim3 grid(Tt, Bb), blk(256);
    gate1_kernel<<<grid, blk, 0, stream>>>(
        (const float*)d_in[0], (const float*)d_in[1], (const float*)d_in[2], (const float*)d_in[3],
        (const float*)d_in[4], (const float*)d_in[5], (const float*)d_in[6], bufA);

    gate_mfma<2, 0><<<grid, blk, 0, stream>>>(bufA, wpre,        bpre,      bufB);
    gate_mfma<4, 0><<<grid, blk, 0, stream>>>(bufB, wpre + 20480, bpre + 32, bufA);
    gate_mfma<8, 1><<<grid, blk, 0, stream>>>(bufA, wpre + 40960, bpre + 64, bufB);

    // GRU reads fp32 gruIn (bufB), writes partials into bufA
    gru_kernel<<<Bb * 8 * 4, 64, 0, stream>>>(
        (const float*)bufB, (const float*)d_in[25], (const float*)d_in[26], (const float*)d_in[27],
        (const float*)d_in[28], (const float*)d_in[29], (float*)bufA);

    out_kernel<<<(Bb * TF / 4) / 256, 256, 0, stream>>>(
        (const float*)bufA, (const float*)d_in[30], (float*)d_out);
}

// Round 3
// 580.633 us; speedup vs baseline: 1.4571x; 1.1321x over previous
//
#include <hip/hip_runtime.h>
#include <math.h>

#define Bb 8
#define Tt 512
#define Ff 256
#define Cc 16
#define TF (Tt*Ff)
#define TROW 528
#define FROW 272
#define CELL 64
#define ROWBYTES (FROW*CELL)                       // 17408
#define BUFBYTES ((size_t)Bb*TROW*FROW*CELL)       // 73,531,392

typedef __attribute__((ext_vector_type(8))) short short8;
typedef __attribute__((ext_vector_type(4))) float f32x4;

typedef const __attribute__((address_space(1))) void* gas1_t;
typedef __attribute__((address_space(3))) void* las3_t;
#define GLOAD_LDS(g, l) __builtin_amdgcn_global_load_lds((gas1_t)(const void*)(g), (las3_t)(void*)(l), 16, 0, 0)

__device__ __forceinline__ float fast_sigmoid(float x) {
    return __builtin_amdgcn_rcpf(1.0f + __expf(-x));
}
__device__ __forceinline__ float fast_tanh(float x) {
    return 1.0f - 2.0f * __builtin_amdgcn_rcpf(__expf(2.0f * x) + 1.0f);
}

__device__ __forceinline__ unsigned short bf16_rne(float x) {
    unsigned u = __float_as_uint(x);
    u += 0x7fffu + ((u >> 16) & 1u);
    return (unsigned short)(u >> 16);
}
__device__ __forceinline__ float bf16_to_f(unsigned short h) {
    return __uint_as_float(((unsigned)h) << 16);
}
__device__ __forceinline__ f32x4 mfma_bf16(short8 a, short8 b, f32x4 c) {
    return __builtin_amdgcn_mfma_f32_16x16x32_bf16(a, b, c, 0, 0, 0);
}

// ---------- zero the halo pads of bufA and bufB (re-poisoned every launch) ----------
__global__ __launch_bounds__(256) void padzero(char* __restrict__ bufA, char* __restrict__ bufB)
{
    int idx = blockIdx.x * 256 + threadIdx.x;      // 200704 cells total
    int which = idx >= 100352;
    int r0 = which ? idx - 100352 : idx;
    int b = r0 / 12544, c = r0 - b * 12544;
    int tp, fp;
    if (c < 4352) { int row = c / 272; fp = c - row * 272; tp = row < 8 ? row : 512 + row; }
    else { int c2 = c - 4352; tp = 8 + (c2 >> 4); int fi = c2 & 15; fp = fi < 8 ? fi : 256 + fi; }
    char* base = (which ? bufB : bufA) + ((size_t)(b * TROW + tp) * FROW + fp) * CELL;
    float4 z = make_float4(0.f, 0.f, 0.f, 0.f);
    float4* p = (float4*)base;
    p[0] = z; p[1] = z; p[2] = z; p[3] = z;
}

// ---------- fold BN into weights, split bf16 hi/lo, write swizzled A-fragment layout ----------
__global__ __launch_bounds__(256) void wsetup(const float* __restrict__ w, const float* __restrict__ bias,
                       const float* __restrict__ gamma, const float* __restrict__ beta,
                       const float* __restrict__ mean, const float* __restrict__ var,
                       char* __restrict__ wpre, float* __restrict__ bpre)
{
    int tid = threadIdx.x;
    if (tid < 32) {
        float s = gamma[tid] * rsqrtf(var[tid] + 1e-5f);
        bpre[tid] = (bias[tid] - mean[tid]) * s + beta[tid];
    }
    for (int i = tid; i < 4608; i += 256) {
        int co = i / 144, r = i - co * 144;
        int ci = r / 9, tap = r - ci * 9;
        float s = gamma[co] * rsqrtf(var[co] + 1e-5f);
        float wv = w[(co * 16 + ci) * 9 + tap] * s;
        unsigned short hi = bf16_rne(wv);
        unsigned short lo = bf16_rne(wv - bf16_to_f(hi));
        int ks = tap >> 1, tp = tap & 1;
        int kl = tp * 16 + ci;
        int qq = kl >> 3, jj = kl & 7;
        int sub = qq ^ (co & 3);
        *(unsigned short*)(wpre + ((0 * 5 + ks) * 32 + co) * 64 + sub * 16 + jj * 2) = hi;
        *(unsigned short*)(wpre + ((1 * 5 + ks) * 32 + co) * 64 + sub * 16 + jj * 2) = lo;
    }
    // zero the pad half of k-step 4 (k_local 16..31), both planes
    for (int i = tid; i < 1024; i += 256) {
        int p = i >> 9, rem = i & 511;
        int co = rem >> 4, kl = 16 + (rem & 15);
        int qq = kl >> 3, jj = kl & 7;
        int sub = qq ^ (co & 3);
        *(unsigned short*)(wpre + ((p * 5 + 4) * 32 + co) * 64 + sub * 16 + jj * 2) = 0;
    }
}

// ---------- conv1 (CIN=2, dil=1): vector kernel, writes padded swizzled bf16 hi/lo layout ----------
__global__ __launch_bounds__(256)
void gate1_kernel(const float* __restrict__ x, const float* __restrict__ w,
                  const float* __restrict__ bias, const float* __restrict__ gamma,
                  const float* __restrict__ beta, const float* __restrict__ mean,
                  const float* __restrict__ var, char* __restrict__ outBuf)
{
    constexpr int CIN = 2;
    __shared__ float wlds[CIN * 32 * 9];
    const int t = blockIdx.x, b = blockIdx.y;
    const int tid = threadIdx.x;
    const int cg = tid >> 5;
    const int f0 = (tid & 31) * 8;

    for (int idx = tid; idx < CIN * 32 * 9; idx += 256) {
        int ci = idx / 288, r = idx - ci * 288;
        int cgi = r / 36, r2 = r - cgi * 36;
        int j = r2 / 9, k = r2 - j * 9;
        int co = 2 * cgi + (j & 1) + (j >> 1) * 16;
        wlds[idx] = w[(co * CIN + ci) * 9 + k];
    }
    __syncthreads();

    float bns[4], bno[4], acc[4][8];
    #pragma unroll
    for (int j = 0; j < 4; j++) {
        int c = 2 * cg + (j & 1) + (j >> 1) * 16;
        float s = gamma[c] * rsqrtf(var[c] + 1e-5f);
        bns[j] = s; bno[j] = beta[c] - mean[c] * s;
        float bi = bias[c];
        #pragma unroll
        for (int q = 0; q < 8; q++) acc[j][q] = bi;
    }

    for (int ci = 0; ci < CIN; ci++) {
        float wr[36];
        const float4* wv4 = (const float4*)(wlds + ci * 288 + cg * 36);
        #pragma unroll
        for (int v = 0; v < 9; v++) ((float4*)wr)[v] = wv4[v];
        #pragma unroll
        for (int dt = 0; dt < 3; dt++) {
            int t_in = t + dt - 1;
            bool trow = (t_in >= 0) && (t_in < Tt);
            const float* rowp = x + ((size_t)(b * CIN + ci) * Tt + (trow ? t_in : 0)) * Ff;
            float buf[16];
            #pragma unroll
            for (int v = 0; v < 4; v++) {
                int fb = f0 - 4 + v * 4;
                float4 val = make_float4(0.f, 0.f, 0.f, 0.f);
                if (trow && fb >= 0 && fb <= Ff - 4) val = *(const float4*)(rowp + fb);
                buf[v*4+0] = val.x; buf[v*4+1] = val.y; buf[v*4+2] = val.z; buf[v*4+3] = val.w;
            }
            #pragma unroll
            for (int kf = 0; kf < 3; kf++)
                #pragma unroll
                for (int j = 0; j < 4; j++) {
                    float wj = wr[j * 9 + dt * 3 + kf];
                    #pragma unroll
                    for (int q = 0; q < 8; q++)
                        acc[j][q] = fmaf(buf[4 + q + kf - 1], wj, acc[j][q]);
                }
        }
    }

    float res[2][8];
    #pragma unroll
    for (int jj = 0; jj < 2; jj++)
        #pragma unroll
        for (int q = 0; q < 8; q++) {
            float a = acc[jj][q] * bns[jj] + bno[jj];
            float g = acc[jj + 2][q] * bns[jj + 2] + bno[jj + 2];
            res[jj][q] = fast_tanh(a) * fast_sigmoid(g);
        }
    // write 2 channels (2cg, 2cg+1) hi+lo into swizzled cells
    #pragma unroll
    for (int q = 0; q < 8; q++) {
        int fp = f0 + q + 8;
        char* cell = outBuf + ((size_t)(b * TROW + t + 8) * FROW + fp) * CELL;
        unsigned short h0 = bf16_rne(res[0][q]), h1 = bf16_rne(res[1][q]);
        unsigned short l0 = bf16_rne(res[0][q] - bf16_to_f(h0));
        unsigned short l1 = bf16_rne(res[1][q] - bf16_to_f(h1));
        unsigned hw = (unsigned)h0 | ((unsigned)h1 << 16);
        unsigned lw = (unsigned)l0 | ((unsigned)l1 << 16);
        int inner = (4 * cg) & 15;
        int sub_hi = (cg >> 2) ^ (fp & 3);
        int sub_lo = (2 + (cg >> 2)) ^ (fp & 3);
        *(unsigned*)(cell + sub_hi * 16 + inner) = hw;
        *(unsigned*)(cell + sub_lo * 16 + inner) = lw;
    }
}

// ---------- convs 2-4: MFMA implicit GEMM, bf16 hi/lo 3-pass ----------
template<int DIL, int WRITE_F32>
__global__ __launch_bounds__(256, 2)
void gate_mfma(const char* __restrict__ actIn, const char* __restrict__ wpre,
               const float* __restrict__ bpre, char* __restrict__ outBuf)
{
    __shared__ char actL[3 * ROWBYTES];    // 52224 B
    const int t = blockIdx.x, b = blockIdx.y;
    const int tid = threadIdx.x;
    const int wv = tid >> 6, lane = tid & 63;
    const int n = lane & 15, q = lane >> 4;

    // A-fragments (weights) from global (L2-hot), registers
    short8 aH[5][2], aL[5][2];
    #pragma unroll
    for (int ks = 0; ks < 5; ks++)
        #pragma unroll
        for (int ct = 0; ct < 2; ct++) {
            int co = ct * 16 + n;
            int sub = q ^ (co & 3);
            aH[ks][ct] = *(const short8*)(wpre + (size_t)((0 * 5 + ks) * 32 + co) * 64 + sub * 16);
            aL[ks][ct] = *(const short8*)(wpre + (size_t)((5 + ks) * 32 + co) * 64 + sub * 16);
        }

    // stage 3 act rows (t-d, t, t+d), contiguous 1088 chunks each
    #pragma unroll
    for (int r = 0; r < 3; r++) {
        int tp = t + 8 + (r - 1) * DIL;
        const char* src = actIn + ((size_t)(b * TROW + tp) * FROW) * CELL;
        char* dst = actL + r * ROWBYTES;
        #pragma unroll
        for (int i = 0; i < 4; i++)
            GLOAD_LDS(src + (i * 256 + tid) * 16, dst + (i * 256 + wv * 64) * 16);
        if (tid < 64)
            GLOAD_LDS(src + (1024 + lane) * 16, dst + 1024 * 16);
    }
    __syncthreads();

    const int fb = wv * 64;
    f32x4 acc[4][2] = {};

    #pragma unroll
    for (int ks = 0; ks < 5; ks++) {
        const int tapA = 2 * ks;
        const int tapB = (2 * ks + 1 > 8) ? 8 : 2 * ks + 1;
        const int rowA = tapA / 3, dfA = (tapA % 3 - 1) * DIL;
        const int rowB = tapB / 3, dfB = (tapB % 3 - 1) * DIL;
        int tapSel = q >> 1;
        int row = tapSel ? rowB : rowA;
        int df  = tapSel ? dfB : dfA;
        int cih = q & 1;
        const char* rbase = actL + row * ROWBYTES;
        #pragma unroll
        for (int nt = 0; nt < 4; nt++) {
            int fp = fb + nt * 16 + n + 8 + df;
            const char* cell = rbase + fp * CELL;
            short8 bH = *(const short8*)(cell + ((cih) ^ (fp & 3)) * 16);
            short8 bL = *(const short8*)(cell + ((2 + cih) ^ (fp & 3)) * 16);
            #pragma unroll
            for (int ct = 0; ct < 2; ct++) {
                acc[nt][ct] = mfma_bf16(aH[ks][ct], bH, acc[nt][ct]);
                acc[nt][ct] = mfma_bf16(aL[ks][ct], bH, acc[nt][ct]);
                acc[nt][ct] = mfma_bf16(aH[ks][ct], bL, acc[nt][ct]);
            }
        }
    }

    // epilogue: GLU, then store
    float4 bA = *(const float4*)(bpre + q * 4);
    float4 bG = *(const float4*)(bpre + 16 + q * 4);
    #pragma unroll
    for (int nt = 0; nt < 4; nt++) {
        float r[4];
        r[0] = fast_tanh(acc[nt][0].x + bA.x) * fast_sigmoid(acc[nt][1].x + bG.x);
        r[1] = fast_tanh(acc[nt][0].y + bA.y) * fast_sigmoid(acc[nt][1].y + bG.y);
        r[2] = fast_tanh(acc[nt][0].z + bA.z) * fast_sigmoid(acc[nt][1].z + bG.z);
        r[3] = fast_tanh(acc[nt][0].w + bA.w) * fast_sigmoid(acc[nt][1].w + bG.w);
        int f = fb + nt * 16 + n;
        if (WRITE_F32) {
            float* gp = (float*)outBuf;
            #pragma unroll
            for (int j = 0; j < 4; j++)
                gp[((size_t)(b * 16 + q * 4 + j) * Tt + t) * Ff + f] = r[j];
        } else {
            int fp = f + 8;
            char* cell = outBuf + ((size_t)(b * TROW + t + 8) * FROW + fp) * CELL;
            unsigned short h[4], l[4];
            #pragma unroll
            for (int j = 0; j < 4; j++) {
                h[j] = bf16_rne(r[j]);
                l[j] = bf16_rne(r[j] - bf16_to_f(h[j]));
            }
            uint2 hw, lw;
            hw.x = (unsigned)h[0] | ((unsigned)h[1] << 16);
            hw.y = (unsigned)h[2] | ((unsigned)h[3] << 16);
            lw.x = (unsigned)l[0] | ((unsigned)l[1] << 16);
            lw.y = (unsigned)l[2] | ((unsigned)l[3] << 16);
            int inner = (q & 1) * 8;
            *(uint2*)(cell + (((q >> 1) ^ (fp & 3)) * 16) + inner) = hw;
            *(uint2*)(cell + (((2 + (q >> 1)) ^ (fp & 3)) * 16) + inner) = lw;
        }
    }
}

// ---------- grouped GRU (H=2) + fused out_w partial dot ----------
// Register ping-pong prefetch: loads issued 32 steps ahead of use (~2500 cy cover).
__global__ __launch_bounds__(64)
void gru_kernel(const float* __restrict__ xin, const float* __restrict__ wih,
                const float* __restrict__ whh, const float* __restrict__ bih,
                const float* __restrict__ bhh, const float* __restrict__ out_w,
                float* __restrict__ part)
{
    const int f = (blockIdx.x & 3) * 64 + threadIdx.x;
    const int g = (blockIdx.x >> 2) & 7;
    const int b = blockIdx.x >> 5;

    float Wih[6][2], Whh[6][2], Bih[6], Bhh[6];
    #pragma unroll
    for (int k = 0; k < 6; k++) {
        Wih[k][0] = wih[g * 12 + k * 2 + 0];
        Wih[k][1] = wih[g * 12 + k * 2 + 1];
        Whh[k][0] = whh[g * 12 + k * 2 + 0];
        Whh[k][1] = whh[g * 12 + k * 2 + 1];
        Bih[k] = bih[g * 6 + k];
        Bhh[k] = bhh[g * 6 + k];
    }
    const float ow0 = out_w[2 * g], ow1 = out_w[2 * g + 1];
    const float* p0 = xin + (size_t)(b * Cc + 2 * g) * TF + f;
    const float* p1 = p0 + TF;
    float* po = part + (size_t)(b * 8 + g) * TF + f;

    float h0 = 0.f, h1 = 0.f;
    // two ping-pong register buffers of 16 steps each
    float a0[16], a1[16], c0[16], c1[16];
    #pragma unroll
    for (int j = 0; j < 16; j++) { a0[j] = p0[j * Ff];        a1[j] = p1[j * Ff]; }
    #pragma unroll
    for (int j = 0; j < 16; j++) { c0[j] = p0[(16 + j) * Ff]; c1[j] = p1[(16 + j) * Ff]; }

    #define GRU_STEP(tt, x0v, x1v)                                          \
    {                                                                        \
        float gi[6], gh[6];                                                  \
        _Pragma("unroll")                                                    \
        for (int k = 0; k < 6; k++) {                                        \
            gi[k] = fmaf(Wih[k][0], (x0v), fmaf(Wih[k][1], (x1v), Bih[k]));  \
            gh[k] = fmaf(Whh[k][0], h0, fmaf(Whh[k][1], h1, Bhh[k]));        \
        }                                                                    \
        float r0 = fast_sigmoid(gi[0] + gh[0]);                              \
        float r1 = fast_sigmoid(gi[1] + gh[1]);                              \
        float z0 = fast_sigmoid(gi[2] + gh[2]);                              \
        float z1 = fast_sigmoid(gi[3] + gh[3]);                              \
        float n0 = fast_tanh(gi[4] + r0 * gh[4]);                            \
        float n1 = fast_tanh(gi[5] + r1 * gh[5]);                            \
        h0 = (1.0f - z0) * n0 + z0 * h0;                                     \
        h1 = (1.0f - z1) * n1 + z1 * h1;                                     \
        po[(tt) * Ff] = fmaf(h0, ow0, h1 * ow1);                             \
    }

    for (int t0 = 0; t0 < Tt; t0 += 32) {
        const bool pfA = (t0 + 32 < Tt);
        #pragma unroll
        for (int j = 0; j < 16; j++) {
            float x0 = a0[j], x1 = a1[j];
            if (pfA) { a0[j] = p0[(t0 + 32 + j) * Ff]; a1[j] = p1[(t0 + 32 + j) * Ff]; }
            GRU_STEP(t0 + j, x0, x1);
        }
        const bool pfB = (t0 + 48 < Tt);
        #pragma unroll
        for (int j = 0; j < 16; j++) {
            float x0 = c0[j], x1 = c1[j];
            if (pfB) { c0[j] = p0[(t0 + 48 + j) * Ff]; c1[j] = p1[(t0 + 48 + j) * Ff]; }
            GRU_STEP(t0 + 16 + j, x0, x1);
        }
    }
    #undef GRU_STEP
}

__global__ __launch_bounds__(256)
void out_kernel(const float* __restrict__ part, const float* __restrict__ out_b,
                float* __restrict__ out)
{
    int idx = (blockIdx.x * 256 + threadIdx.x) * 4;
    int b = idx / TF;
    int r = idx - b * TF;
    const float4* p = (const float4*)(part + (size_t)b * 8 * TF + r);
    float ob = out_b[0];
    float4 s = make_float4(ob, ob, ob, ob);
    #pragma unroll
    for (int g = 0; g < 8; g++) {
        float4 v = p[(size_t)g * (TF / 4)];
        s.x += v.x; s.y += v.y; s.z += v.z; s.w += v.w;
    }
    *(float4*)(out + idx) = s;
}

extern "C" void kernel_launch(void* const* d_in, const int* in_sizes, int n_in,
                              void* d_out, int out_size, void* d_ws, size_t ws_size,
                              hipStream_t stream) {
    char* bufA = (char*)d_ws;
    char* bufB = bufA + BUFBYTES;
    char* wpre = bufB + BUFBYTES;
    float* bpre = (float*)(wpre + 3 * 20480);

    padzero<<<784, 256, 0, stream>>>(bufA, bufB);
    wsetup<<<1, 256, 0, stream>>>((const float*)d_in[7],  (const float*)d_in[8],  (const float*)d_in[9],
                                  (const float*)d_in[10], (const float*)d_in[11], (const float*)d_in[12],
                                  wpre, bpre);
    wsetup<<<1, 256, 0, stream>>>((const float*)d_in[13], (const float*)d_in[14], (const float*)d_in[15],
                                  (const float*)d_in[16], (const float*)d_in[17], (const float*)d_in[18],
                                  wpre + 20480, bpre + 32);
    wsetup<<<1, 256, 0, stream>>>((const float*)d_in[19], (const float*)d_in[20], (const float*)d_in[21],
                                  (const float*)d_in[22], (const float*)d_in[23], (const float*)d_in[24],
                                  wpre + 40960, bpre + 64);

    dim3 grid(Tt, Bb), blk(256);
    gate1_kernel<<<grid, blk, 0, stream>>>(
        (const float*)d_in[0], (const float*)d_in[1], (const float*)d_in[2], (const float*)d_in[3],
        (const float*)d_in[4], (const float*)d_in[5], (const float*)d_in[6], bufA);

    gate_mfma<2, 0><<<grid, blk, 0, stream>>>(bufA, wpre,        bpre,      bufB);
    gate_mfma<4, 0><<<grid, blk, 0, stream>>>(bufB, wpre + 20480, bpre + 32, bufA);
    gate_mfma<8, 1><<<grid, blk, 0, stream>>>(bufA, wpre + 40960, bpre + 64, bufB);

    // GRU reads fp32 gruIn (bufB), writes partials into bufA
    gru_kernel<<<Bb * 8 * 4, 64, 0, stream>>>(
        (const float*)bufB, (const float*)d_in[25], (const float*)d_in[26], (const float*)d_in[27],
        (const float*)d_in[28], (const float*)d_in[29], (float*)bufA);

    out_kernel<<<(Bb * TF / 4) / 256, 256, 0, stream>>>(
        (const float*)bufA, (const float*)d_in[30], (float*)d_out);
}